// Round 1
// baseline (800.692 us; speedup 1.0000x reference)
//
#include <hip/hip_runtime.h>

typedef unsigned short u16;
typedef u16 u16x4 __attribute__((ext_vector_type(4)));
typedef u16 u16x8 __attribute__((ext_vector_type(8)));
typedef short bf16x8 __attribute__((ext_vector_type(8)));
typedef float f32x4 __attribute__((ext_vector_type(4)));

static __device__ __forceinline__ u16 f2bf(float f) {
  union { float f; unsigned u; } v; v.f = f;
  unsigned r = v.u + 0x7FFFu + ((v.u >> 16) & 1u);
  return (u16)(r >> 16);
}

// Problem constants: B=32, L=512 (KL=QL), E=1024 (EK=EQ), H=8, D=128, OUT=1024
// score layout: (H*B, 512, 512) head-major (hb = h*32 + b)
// ctx layout:   (B, 512, H*128)

// ---------------------------------------------------------------------------
// Generic C = A @ Bt^T GEMM.  A: MxK (f32 or bf16), Bt: NxK row-major bf16.
// C: MxN (bf16 or f32).  Optional transposed copy Ct (kxT, hardcoded geometry)
// and bias add.  Tile 128x128, BK=64, 256 threads = 4 waves (2x2 of 64x64).
// Batched via blockIdx.z decomposed as zH=z>>5, zB=z&31 with per-operand strides.
// ---------------------------------------------------------------------------
template<bool A_F32, bool OUT_F32, bool WRITE_T, bool BIAS>
__global__ __launch_bounds__(256)
void gemm_bt(const void* __restrict__ A_, const u16* __restrict__ Bt,
             void* __restrict__ C_, u16* __restrict__ Ct,
             const float* __restrict__ bias,
             int M, int N, int K, int lda, int ldb, int ldc,
             long aSH, long aSB, long bSH, long bSB, long cSH, long cSB)
{
  constexpr int BM = 128, BN = 128, BK = 64, LDS_K = 72; // 72*2=144B rows: 16B-aligned, 2-way banks
  __shared__ __align__(16) u16 As[BM][LDS_K];
  __shared__ __align__(16) u16 Bs[BN][LDS_K];

  const int tid  = threadIdx.x;
  const int lane = tid & 63;
  const int w    = tid >> 6;
  const int wr   = w >> 1, wc = w & 1;
  const int brow = blockIdx.y * BM;
  const int bcol = blockIdx.x * BN;
  const int zH = blockIdx.z >> 5, zB = blockIdx.z & 31;
  const long offA = (long)zH * aSH + (long)zB * aSB;
  const long offB = (long)zH * bSH + (long)zB * bSB;
  const long offC = (long)zH * cSH + (long)zB * cSB;
  const int kgrp = lane >> 4;   // 0..3
  const int l16  = lane & 15;

  f32x4 acc[4][4];
#pragma unroll
  for (int m = 0; m < 4; ++m)
#pragma unroll
    for (int n = 0; n < 4; ++n) acc[m][n] = f32x4{0.f, 0.f, 0.f, 0.f};

  for (int kt = 0; kt < K; kt += BK) {
    // ---- stage A tile (BM x BK) ----
    if constexpr (A_F32) {
      const float* A = (const float*)A_ + offA;
#pragma unroll
      for (int i = 0; i < 8; ++i) {
        int idx = i * 256 + tid;          // 0..2047 ; 16 float4 per row
        int row = idx >> 4, c4 = idx & 15;
        float4 v = *(const float4*)(A + (long)(brow + row) * lda + kt + c4 * 4);
        u16x4 b;
        b[0] = f2bf(v.x); b[1] = f2bf(v.y); b[2] = f2bf(v.z); b[3] = f2bf(v.w);
        *(u16x4*)(&As[row][c4 * 4]) = b;
      }
    } else {
      const u16* A = (const u16*)A_ + offA;
#pragma unroll
      for (int i = 0; i < 4; ++i) {
        int idx = i * 256 + tid;          // 0..1023 ; 8 chunks of 8 bf16 per row
        int row = idx >> 3, c8 = idx & 7;
        *(u16x8*)(&As[row][c8 * 8]) =
            *(const u16x8*)(A + (long)(brow + row) * lda + kt + c8 * 8);
      }
    }
    // ---- stage B tile (BN x BK), always bf16 ----
#pragma unroll
    for (int i = 0; i < 4; ++i) {
      int idx = i * 256 + tid;
      int row = idx >> 3, c8 = idx & 7;
      *(u16x8*)(&Bs[row][c8 * 8]) =
          *(const u16x8*)(Bt + offB + (long)(bcol + row) * ldb + kt + c8 * 8);
    }
    __syncthreads();
    // ---- compute: 2 MFMA K-steps of 32 ----
#pragma unroll
    for (int kk = 0; kk < 2; ++kk) {
      bf16x8 af[4], bf[4];
#pragma unroll
      for (int m = 0; m < 4; ++m)
        af[m] = *(const bf16x8*)(&As[wr * 64 + m * 16 + l16][kk * 32 + kgrp * 8]);
#pragma unroll
      for (int n = 0; n < 4; ++n)
        bf[n] = *(const bf16x8*)(&Bs[wc * 64 + n * 16 + l16][kk * 32 + kgrp * 8]);
#pragma unroll
      for (int m = 0; m < 4; ++m)
#pragma unroll
        for (int n = 0; n < 4; ++n)
          acc[m][n] = __builtin_amdgcn_mfma_f32_16x16x32_bf16(af[m], bf[n], acc[m][n], 0, 0, 0);
    }
    __syncthreads();
  }

  // ---- epilogue ----
#pragma unroll
  for (int m = 0; m < 4; ++m) {
    const int gr0 = brow + wr * 64 + m * 16 + kgrp * 4;  // 4 consecutive rows (j)
#pragma unroll
    for (int n = 0; n < 4; ++n) {
      const int gc = bcol + wc * 64 + n * 16 + l16;
      if constexpr (OUT_F32) {
        float* C = (float*)C_ + offC;
        const float bv = BIAS ? bias[gc] : 0.0f;
#pragma unroll
        for (int j = 0; j < 4; ++j)
          C[(long)(gr0 + j) * ldc + gc] = acc[m][n][j] + bv;
      } else {
        u16* C = (u16*)C_ + offC;
#pragma unroll
        for (int j = 0; j < 4; ++j)
          C[(long)(gr0 + j) * ldc + gc] = f2bf(acc[m][n][j]);
        if constexpr (WRITE_T) {
          // kxT[((gc>>7)*32 + (gr>>9))*65536 + (gc&127)*512 + (gr&511)], 4 rows packed
          u16x4 t;
#pragma unroll
          for (int j = 0; j < 4; ++j) t[j] = f2bf(acc[m][n][j]);
          long ti = ((long)(gc >> 7) * 32 + (gr0 >> 9)) * 65536 + (long)(gc & 127) * 512 + (gr0 & 511);
          *(u16x4*)(Ct + ti) = t;
        }
      }
    }
  }
}

// ---------------------------------------------------------------------------
// Attention scores + softmax.  One block = (h, b, 64 q-rows).  4 waves, each
// wave owns 16 q-rows x all 512 k-cols in registers (32 x f32x4 / lane).
// K rows staged in LDS (64x128 bf16, padded).  Softmax wave-parallel via
// shfl_xor across the 16-lane column group.  P written f32 to d_out score.
// ---------------------------------------------------------------------------
__global__ __launch_bounds__(256)
void attn_scores(const u16* __restrict__ qx, const u16* __restrict__ kx,
                 float* __restrict__ score)
{
  __shared__ __align__(16) u16 Ks[64][136];   // 272B rows: 16B-aligned, ~2-way banks
  const int tid = threadIdx.x, lane = tid & 63, w = tid >> 6;
  const int bid = blockIdx.x;
  const int qt = bid & 7, hb = bid >> 3, h = hb >> 5, b = hb & 31;
  const int kgrp = lane >> 4, l16 = lane & 15;

  // Q fragments for this wave's 16 rows (read once)
  const u16* qrow = qx + ((long)(b * 512 + qt * 64 + w * 16 + l16)) * 1024 + h * 128 + kgrp * 8;
  bf16x8 qf[4];
#pragma unroll
  for (int kk = 0; kk < 4; ++kk) qf[kk] = *(const bf16x8*)(qrow + kk * 32);

  f32x4 acc[32];
#pragma unroll
  for (int n = 0; n < 32; ++n) acc[n] = f32x4{0.f, 0.f, 0.f, 0.f};

  const u16* kbase = kx + (long)b * 512 * 1024 + h * 128;
#pragma unroll
  for (int chunk = 0; chunk < 8; ++chunk) {
    __syncthreads();
    // stage 64 K-rows x 128
#pragma unroll
    for (int i = 0; i < 4; ++i) {
      int idx = i * 256 + tid;       // 0..1023 ; 16 chunks of 8 per row
      int row = idx >> 4, c8 = idx & 15;
      *(u16x8*)(&Ks[row][c8 * 8]) =
          *(const u16x8*)(kbase + (long)(chunk * 64 + row) * 1024 + c8 * 8);
    }
    __syncthreads();
#pragma unroll
    for (int kk = 0; kk < 4; ++kk)
#pragma unroll
      for (int nl = 0; nl < 4; ++nl) {
        bf16x8 bf = *(const bf16x8*)(&Ks[nl * 16 + l16][kk * 32 + kgrp * 8]);
        acc[chunk * 4 + nl] =
            __builtin_amdgcn_mfma_f32_16x16x32_bf16(qf[kk], bf, acc[chunk * 4 + nl], 0, 0, 0);
      }
  }

  // softmax over 512 cols per row; row r = kgrp*4 + j, cols spread over l16 x n
  const float scale = 0.08838834764831845f;  // 1/sqrt(128)
#pragma unroll
  for (int j = 0; j < 4; ++j) {
    float m = -1e30f;
#pragma unroll
    for (int n = 0; n < 32; ++n) m = fmaxf(m, acc[n][j]);
    m = fmaxf(m, __shfl_xor(m, 1));
    m = fmaxf(m, __shfl_xor(m, 2));
    m = fmaxf(m, __shfl_xor(m, 4));
    m = fmaxf(m, __shfl_xor(m, 8));
    float s = 0.f;
#pragma unroll
    for (int n = 0; n < 32; ++n) {
      float e = __expf((acc[n][j] - m) * scale);
      acc[n][j] = e; s += e;
    }
    s += __shfl_xor(s, 1);
    s += __shfl_xor(s, 2);
    s += __shfl_xor(s, 4);
    s += __shfl_xor(s, 8);
    float inv = 1.0f / s;
#pragma unroll
    for (int n = 0; n < 32; ++n) acc[n][j] *= inv;
  }

  // write P f32
  float* srow = score + ((long)hb * 512 + qt * 64 + w * 16 + kgrp * 4) * 512 + l16;
#pragma unroll
  for (int j = 0; j < 4; ++j)
#pragma unroll
    for (int n = 0; n < 32; ++n)
      srow[(long)j * 512 + n * 16] = acc[n][j];
}

// ---------------------------------------------------------------------------
// Weight packing
// ---------------------------------------------------------------------------
// w (H=8, E=1024, D=128) f32 -> wT[(h*128+d)*1024 + e] bf16
__global__ __launch_bounds__(256)
void pack_whead(const float* __restrict__ w, u16* __restrict__ wT)
{
  long i = (long)blockIdx.x * 256 + threadIdx.x;   // i = n*1024 + e
  int n = (int)(i >> 10), e = (int)(i & 1023);
  int h = n >> 7, d = n & 127;
  wT[i] = f2bf(w[((long)h * 1024 + e) * 128 + d]);
}

// straight f32 -> bf16 convert (proj_w), vectorized x4
__global__ __launch_bounds__(256)
void pack_pw(const float4* __restrict__ w, u16x4* __restrict__ o)
{
  long i = (long)blockIdx.x * 256 + threadIdx.x;
  float4 v = w[i];
  u16x4 t;
  t[0] = f2bf(v.x); t[1] = f2bf(v.y); t[2] = f2bf(v.z); t[3] = f2bf(v.w);
  o[i] = t;
}

// ---------------------------------------------------------------------------
extern "C" void kernel_launch(void* const* d_in, const int* in_sizes, int n_in,
                              void* d_out, int out_size, void* d_ws, size_t ws_size,
                              hipStream_t stream)
{
  const float* k      = (const float*)d_in[0];   // (32,512,1024)
  const float* q      = (const float*)d_in[1];   // (32,512,1024)
  const float* w_kx   = (const float*)d_in[2];   // (8,1024,128)
  const float* w_qx   = (const float*)d_in[3];   // (8,1024,128)
  const float* proj_w = (const float*)d_in[4];   // (1024,1024)
  const float* proj_b = (const float*)d_in[5];   // (1024,)

  float* out   = (float*)d_out;                  // 32*512*1024 = 16777216
  float* score = (float*)d_out + 16777216;       // 256*512*512 = 67108864

  char* ws = (char*)d_ws;
  u16* wkT = (u16*)(ws + 0);              //  2 MB : (1024,1024) bf16, Bt[h*128+d][e]
  u16* wqT = (u16*)(ws + (2l << 20));     //  2 MB
  u16* pwB = (u16*)(ws + (4l << 20));     //  2 MB : proj_w bf16 (row-major NxK)
  u16* kx  = (u16*)(ws + (6l << 20));     // 33.5 MB : (b,kl,h*128+d) bf16
  u16* qx  = (u16*)(ws + 39845888l);      // 33.5 MB
  u16* kxT = (u16*)(ws + 73400320l);      // 33.5 MB : (hb, d, kl) bf16
  u16* ctx = (u16*)(ws + 106954752l);     // 33.5 MB : (b,q,h*128+d) bf16

  // 1) pack weights to bf16 (with head-major -> NxK permute for w_kx/w_qx)
  pack_whead<<<4096, 256, 0, stream>>>(w_kx, wkT);
  pack_whead<<<4096, 256, 0, stream>>>(w_qx, wqT);
  pack_pw<<<1024, 256, 0, stream>>>((const float4*)proj_w, (u16x4*)pwB);

  // 2) kx = k @ wkT^T  (also emits kxT);  qx = q @ wqT^T
  gemm_bt<true, false, true, false><<<dim3(8, 128, 1), 256, 0, stream>>>(
      k, wkT, kx, kxT, nullptr, 16384, 1024, 1024, 1024, 1024, 1024,
      0, 0, 0, 0, 0, 0);
  gemm_bt<true, false, false, false><<<dim3(8, 128, 1), 256, 0, stream>>>(
      q, wqT, qx, nullptr, nullptr, 16384, 1024, 1024, 1024, 1024, 1024,
      0, 0, 0, 0, 0, 0);

  // 3) scores + softmax -> d_out score region (f32)
  attn_scores<<<2048, 256, 0, stream>>>(qx, kx, score);

  // 4) ctx = P @ kx   (batched over hb: A=score f32, Bt=kxT)
  gemm_bt<true, false, false, false><<<dim3(1, 4, 256), 256, 0, stream>>>(
      score, kxT, ctx, nullptr, nullptr, 512, 128, 512, 512, 512, 1024,
      8388608l, 262144l, 2097152l, 65536l, 128l, 524288l);

  // 5) out = ctx @ proj_w^T + b
  gemm_bt<false, true, false, true><<<dim3(8, 128, 1), 256, 0, stream>>>(
      ctx, pwB, out, nullptr, proj_b, 16384, 1024, 1024, 1024, 1024, 1024,
      0, 0, 0, 0, 0, 0);
}